// Round 5
// baseline (317.521 us; speedup 1.0000x reference)
//
#include <hip/hip_runtime.h>
#include <cstdint>

// ---------------------------------------------------------------------------
// NEO vision embeddings, MI355X (gfx950) — round 5: barrier-light counted pipe
//   conv:  pixf16[32768][608] (pad 588->608), B1 f16 [1024][608], B2 f16 perm
//   GEMM1: pe = rope(gelu(pixf16 @ B1^T + b1))          (256^2, BK=32, depth-3)
//   GEMM2: out = gather(pe)[8192,4096] @ B2^T + b2      (256^2, BK=32, depth-3)
// Per K32-iter: 12 ds_read (counted lgkm 4/0) + 4 gload_lds + 32 MFMA +
// ONE vmcnt(8) + ONE s_barrier. No per-phase lockstep (AITER-style).
// ---------------------------------------------------------------------------

using f16x8 = __attribute__((ext_vector_type(8))) _Float16;
using f32x4 = __attribute__((ext_vector_type(4))) float;

__device__ __forceinline__ void gload_lds16(const void* g, void* l) {
  __builtin_amdgcn_global_load_lds(
      reinterpret_cast<const __attribute__((address_space(1))) unsigned int*>(
          reinterpret_cast<uintptr_t>(g)),
      reinterpret_cast<__attribute__((address_space(3))) unsigned int*>(
          reinterpret_cast<uintptr_t>(l)),
      16, 0, 0);
}

__device__ __forceinline__ f16x8 ldsr(unsigned addr) {
  f16x8 r;
  asm volatile("ds_read_b128 %0, %1" : "=v"(r) : "v"(addr));
  return r;
}

// -------------------------- conversion kernels -----------------------------

__global__ void conv_b1_kernel(const float* __restrict__ w1,
                               _Float16* __restrict__ h) {
  int i = blockIdx.x * 256 + threadIdx.x;          // over 1024*608
  if (i >= 1024 * 608) return;
  int e = i / 608;
  int k = i - e * 608;
  float v = (k < 588) ? w1[(size_t)e * 588 + k] : 0.0f;
  h[i] = (_Float16)v;
}

__global__ void conv_b2_kernel(const float* __restrict__ w2,
                               _Float16* __restrict__ h) {
  int i = blockIdx.x * 256 + threadIdx.x;          // over 2048*4096
  int o   = i >> 12;
  int rem = i & 4095;
  int pq  = rem >> 10;
  int e   = rem & 1023;
  h[i] = (_Float16)w2[(size_t)o * 4096 + e * 4 + pq];
}

__global__ void conv_pix_kernel(const float* __restrict__ pix,
                                _Float16* __restrict__ h) {
  int i = blockIdx.x * 256 + threadIdx.x;          // over 32768*76
  if (i >= 32768 * 76) return;
  int n = i / 76;
  int g = i - n * 76;
  int k0 = g * 8;
  f16x8 v;
  if (k0 + 8 <= 588) {
    const float4 x0 = *(const float4*)(pix + (size_t)n * 588 + k0);
    const float4 x1 = *(const float4*)(pix + (size_t)n * 588 + k0 + 4);
    v[0] = (_Float16)x0.x; v[1] = (_Float16)x0.y;
    v[2] = (_Float16)x0.z; v[3] = (_Float16)x0.w;
    v[4] = (_Float16)x1.x; v[5] = (_Float16)x1.y;
    v[6] = (_Float16)x1.z; v[7] = (_Float16)x1.w;
  } else {
#pragma unroll
    for (int j = 0; j < 8; ++j) {
      int k = k0 + j;
      v[j] = (k < 588) ? (_Float16)pix[(size_t)n * 588 + k] : (_Float16)0.0f;
    }
  }
  *(f16x8*)(h + (size_t)n * 608 + k0) = v;
}

// ------------------------- shared schedule macros --------------------------

#define DR8 asm volatile("s_waitcnt vmcnt(8)" ::: "memory")
#define DR4 asm volatile("s_waitcnt vmcnt(4)" ::: "memory")
#define DR0 asm volatile("s_waitcnt vmcnt(0)" ::: "memory")
#define NODR ((void)0)

// Per iter kt: read slot kt&3 (12 x ds_read_b128), stage tile kt+3 into slot
// (kt+3)&3, counted lgkm waits interleave reads with 2x16 MFMA, then one
// counted vmcnt drain + one s_barrier. Slot reuse is safe: a slot written at
// iter kt (tile kt+3) was last read at iter kt-1, which ended with a barrier,
// and reads retire before MFMA issue (lgkm) hence before barrier arrival.
#define GEMM_ITER(kt, DOST, STAGE_A, STAGE_B, DRAIN)                       \
  {                                                                        \
    const unsigned sb = base + ((unsigned)((kt) & 3) << 15);               \
    const int st = (kt) + 3;                                               \
    (void)st;                                                              \
    f16x8 a[4], a2[4], b[4];                                               \
    _Pragma("unroll") for (int i = 0; i < 4; ++i)                          \
        a[i] = ldsr(sb + aoffs + (unsigned)(i * 1024));                    \
    _Pragma("unroll") for (int j = 0; j < 4; ++j)                          \
        b[j] = ldsr(sb + boffs + (unsigned)(j * 1024));                    \
    _Pragma("unroll") for (int i = 0; i < 4; ++i)                          \
        a2[i] = ldsr(sb + aoffs + (unsigned)((4 + i) * 1024));             \
    if (DOST) { STAGE_A(st); STAGE_B(st); }                                \
    asm volatile("s_waitcnt lgkmcnt(4)" ::: "memory");                     \
    __builtin_amdgcn_sched_barrier(0);                                     \
    __builtin_amdgcn_s_setprio(1);                                         \
    _Pragma("unroll") for (int i = 0; i < 4; ++i)                          \
        _Pragma("unroll") for (int j = 0; j < 4; ++j)                      \
            acc[i][j] = __builtin_amdgcn_mfma_f32_16x16x32_f16(            \
                a[i], b[j], acc[i][j], 0, 0, 0);                           \
    asm volatile("s_waitcnt lgkmcnt(0)" ::: "memory");                     \
    __builtin_amdgcn_sched_barrier(0);                                     \
    _Pragma("unroll") for (int i = 0; i < 4; ++i)                          \
        _Pragma("unroll") for (int j = 0; j < 4; ++j)                      \
            acc[4 + i][j] = __builtin_amdgcn_mfma_f32_16x16x32_f16(        \
                a2[i], b[j], acc[4 + i][j], 0, 0, 0);                      \
    __builtin_amdgcn_s_setprio(0);                                         \
    DRAIN;                                                                 \
    asm volatile("s_barrier" ::: "memory");                                \
  }

// ------------------------------- GEMM1 -------------------------------------

#define P_STAGE_A(s)                                                       \
  _Pragma("unroll") for (int c = 0; c < 2; ++c) {                          \
    const int m = tA + c * 16;                                             \
    gload_lds16(pixf + (size_t)m * 608 + (s) * 32 + gc,                    \
                &fr[(s) & 3][0][wave * 2 + c][0]);                         \
  }
#define P_STAGE_B(s)                                                       \
  _Pragma("unroll") for (int c = 0; c < 2; ++c) {                          \
    const int e = nB + c * 16;                                             \
    gload_lds16(b1w + (size_t)e * 608 + (s) * 32 + gc,                     \
                &fr[(s) & 3][1][wave * 2 + c][0]);                         \
  }

__global__ __launch_bounds__(512, 2) void patch_gemm8(
    const _Float16* __restrict__ pixf,
    const _Float16* __restrict__ b1w,
    const float* __restrict__ bias1,
    const float* __restrict__ cosx, const float* __restrict__ sinx,
    const float* __restrict__ cosy, const float* __restrict__ siny,
    _Float16* __restrict__ pe)
{
  __shared__ f16x8 fr[4][2][16][64];   // 128 KiB

  const int tid  = threadIdx.x;
  const int lane = tid & 63;
  const int wave = tid >> 6;
  const int wm = wave >> 2;            // 0..1
  const int wn = wave & 3;             // 0..3
  const int bm = blockIdx.x, bn = blockIdx.y;
  const int l15 = lane & 15;
  const int gc  = (lane >> 4) * 8;

  const unsigned base  = (unsigned)(uintptr_t)&fr[0][0][0][0];
  const unsigned aoffs = (unsigned)(wm * 8192 + lane * 16);
  const unsigned boffs = (unsigned)(16384 + wn * 4096 + lane * 16);

  const int bm256 = bm * 256;
  const int tA = bm256 + wave * 32 + l15;          // A stage row base
  const int nB = bn * 256 + wave * 32 + l15;       // B stage row base

  f32x4 acc[8][4] = {};

  // prologue: stage tiles 0,1,2
  P_STAGE_A(0); P_STAGE_B(0);
  P_STAGE_A(1); P_STAGE_B(1);
  P_STAGE_A(2); P_STAGE_B(2);
  DR8;
  asm volatile("s_barrier" ::: "memory");

  for (int kt = 0; kt < 16; ++kt)
    GEMM_ITER(kt, 1, P_STAGE_A, P_STAGE_B, DR8);
  GEMM_ITER(16, 0, P_STAGE_A, P_STAGE_B, DR4);
  GEMM_ITER(17, 0, P_STAGE_A, P_STAGE_B, DR0);
  GEMM_ITER(18, 0, P_STAGE_A, P_STAGE_B, NODR);

  // epilogue: bias + gelu + rope, f16 store
  const int md = (lane >> 4) * 4;
#pragma unroll
  for (int mf = 0; mf < 8; ++mf) {
#pragma unroll
    for (int r = 0; r < 4; ++r) {
      const int m = bm256 + wm * 128 + mf * 16 + md + r;
      const int pid  = m & 4095;
      const int posx = pid & 63;
      const int posy = (pid >> 6) & 63;
#pragma unroll
      for (int nf = 0; nf < 4; ++nf) {
        const int e = bn * 256 + wn * 64 + nf * 16 + l15;
        float v = acc[mf][nf][r] + bias1[e];
        v = 0.5f * v * (1.0f + erff(v * 0.70710678118654752f));
        const float pv = __shfl_xor(v, 1, 64);     // pair partner (e ^ 1)
        const int h2  = (e >= 512) ? 1 : 0;
        const int idx = (h2 ? (e - 512) : e) >> 1;
        const int pos = h2 ? posy : posx;
        const float cc = (h2 ? cosy : cosx)[pos * 256 + idx];
        const float ss = (h2 ? siny : sinx)[pos * 256 + idx];
        const float o = ((lane & 1) == 0) ? (v * cc - pv * ss)
                                          : (pv * ss + v * cc);
        pe[(size_t)m * 1024 + e] = (_Float16)o;
      }
    }
  }
}

// ------------------------------- GEMM2 -------------------------------------

#define D_STAGE_A(s)                                                       \
  {                                                                        \
    const int pq = (s) >> 5, p = pq >> 1, q = pq & 1;                      \
    const int e0 = ((s) & 31) << 5;                                        \
    _Pragma("unroll") for (int c = 0; c < 2; ++c) {                        \
      const int t = tA + c * 16;                                           \
      const int rr = t & 1023;                                             \
      const int prow =                                                     \
          (t >> 10) * 4096 + ((rr >> 5) * 2 + p) * 64 + (rr & 31) * 2 + q; \
      gload_lds16(pe + (size_t)prow * 1024 + e0 + gc,                      \
                  &fr[(s) & 3][0][wave * 2 + c][0]);                       \
    }                                                                      \
  }
#define D_STAGE_B(s)                                                       \
  _Pragma("unroll") for (int c = 0; c < 2; ++c) {                          \
    const int n = nB + c * 16;                                             \
    gload_lds16(b2w + (size_t)n * 4096 + (s) * 32 + gc,                    \
                &fr[(s) & 3][1][wave * 2 + c][0]);                         \
  }

__global__ __launch_bounds__(512, 2) void dense_gemm8(
    const _Float16* __restrict__ pe,
    const _Float16* __restrict__ b2w,
    const float* __restrict__ bias2, float* __restrict__ out)
{
  __shared__ f16x8 fr[4][2][16][64];   // 128 KiB

  const int tid  = threadIdx.x;
  const int lane = tid & 63;
  const int wave = tid >> 6;
  const int wm = wave >> 2;
  const int wn = wave & 3;
  const int bm = blockIdx.x, bn = blockIdx.y;
  const int l15 = lane & 15;
  const int gc  = (lane >> 4) * 8;

  const unsigned base  = (unsigned)(uintptr_t)&fr[0][0][0][0];
  const unsigned aoffs = (unsigned)(wm * 8192 + lane * 16);
  const unsigned boffs = (unsigned)(16384 + wn * 4096 + lane * 16);

  const int bm256 = bm * 256;
  const int tA = bm256 + wave * 32 + l15;
  const int nB = bn * 256 + wave * 32 + l15;

  f32x4 acc[8][4] = {};

  D_STAGE_A(0); D_STAGE_B(0);
  D_STAGE_A(1); D_STAGE_B(1);
  D_STAGE_A(2); D_STAGE_B(2);
  DR8;
  asm volatile("s_barrier" ::: "memory");

  for (int kt = 0; kt < 125; ++kt)
    GEMM_ITER(kt, 1, D_STAGE_A, D_STAGE_B, DR8);
  GEMM_ITER(125, 0, D_STAGE_A, D_STAGE_B, DR4);
  GEMM_ITER(126, 0, D_STAGE_A, D_STAGE_B, DR0);
  GEMM_ITER(127, 0, D_STAGE_A, D_STAGE_B, NODR);

  // epilogue
  const int md = (lane >> 4) * 4;
  const int r0 = bm256 + wm * 128;
  const int c0 = bn * 256 + wn * 64;
#pragma unroll
  for (int nf = 0; nf < 4; ++nf) {
    const int o = c0 + nf * 16 + l15;
    const float bs = bias2[o];
#pragma unroll
    for (int mf = 0; mf < 8; ++mf) {
      const int t = r0 + mf * 16 + md;
#pragma unroll
      for (int r = 0; r < 4; ++r)
        out[(size_t)(t + r) * 2048 + o] = acc[mf][nf][r] + bs;
    }
  }
}

// ----------------------------- launcher ------------------------------------

extern "C" void kernel_launch(void* const* d_in, const int* in_sizes, int n_in,
                              void* d_out, int out_size, void* d_ws, size_t ws_size,
                              hipStream_t stream) {
  const float* pix  = (const float*)d_in[0];
  const float* w1   = (const float*)d_in[2];
  const float* b1   = (const float*)d_in[3];
  const float* w2   = (const float*)d_in[4];
  const float* b2   = (const float*)d_in[5];
  const float* cosx = (const float*)d_in[6];
  const float* sinx = (const float*)d_in[7];
  const float* cosy = (const float*)d_in[8];
  const float* siny = (const float*)d_in[9];
  float* out = (float*)d_out;

  _Float16* ws = (_Float16*)d_ws;
  const size_t PE_N  = (size_t)32768 * 1024;
  const size_t B1_N  = (size_t)1024 * 608;
  const size_t B2_N  = (size_t)2048 * 4096;
  _Float16* peb  = ws;
  _Float16* b1h  = peb + PE_N;
  _Float16* b2h  = b1h + B1_N;
  _Float16* pixf = b2h + B2_N;
  // total ws ~125 MB

  conv_b1_kernel<<<dim3(2432), dim3(256), 0, stream>>>(w1, b1h);
  conv_b2_kernel<<<dim3(32768), dim3(256), 0, stream>>>(w2, b2h);
  conv_pix_kernel<<<dim3(9728), dim3(256), 0, stream>>>(pix, pixf);
  patch_gemm8<<<dim3(128, 4), dim3(512), 0, stream>>>(
      pixf, b1h, b1, cosx, sinx, cosy, siny, peb);
  dense_gemm8<<<dim3(32, 8), dim3(512), 0, stream>>>(
      peb, b2h, b2, out);
}